// Round 1
// baseline (423.673 us; speedup 1.0000x reference)
//
#include <hip/hip_runtime.h>
#include <cstddef>

// Problem shapes (fixed by reference)
#define NBH  1024   // B*H
#define Mm   196
#define Dd   128
#define MIDe 64
#define DVv  128

__device__ __forceinline__ float waveReduceSum(float v) {
#pragma unroll
    for (int off = 32; off > 0; off >>= 1) v += __shfl_xor(v, off, 64);
    return v;
}

__device__ __forceinline__ float waveReduceMax(float v) {
#pragma unroll
    for (int off = 32; off > 0; off >>= 1) v = fmaxf(v, __shfl_xor(v, off, 64));
    return v;
}

__global__ __launch_bounds__(256, 4)
void scatt_fused(const float* __restrict__ query,
                 const float* __restrict__ key,
                 const float* __restrict__ att_mask,
                 const float* __restrict__ value1,
                 const float* __restrict__ value2,
                 const float* __restrict__ W_basic,
                 const float* __restrict__ b_basic,
                 const float* __restrict__ W_spatial,
                 const float* __restrict__ b_spatial,
                 const float* __restrict__ W_channel,
                 const float* __restrict__ b_channel,
                 float* __restrict__ out)
{
    __shared__ float wqS[Dd * MIDe];    // 32 KB: Wq[d][e] = q[d]*W_basic[d][e]
    __shared__ float maskS[Mm];
    __shared__ float sS[Mm];            // spatial logits, then alpha (in place)
    __shared__ float poolPart[4][MIDe];
    __shared__ float poolS[MIDe];
    __shared__ float partS[8][DVv];     // v2 partial sums
    __shared__ float redS[12];

    const int t    = threadIdx.x;
    const int lane = t & 63;            // = e in phase 1
    const int w    = t >> 6;            // wave id 0..3
    const int bh   = blockIdx.x;
    const int b    = bh >> 3;

    const float* __restrict__ keyB  = key      + (size_t)bh * Mm * Dd;
    const float* __restrict__ val2B = value2   + (size_t)bh * Mm * DVv;
    const float* __restrict__ qB    = query    + (size_t)bh * Dd;
    const float* __restrict__ maskB = att_mask + (size_t)b  * Mm;

    // ---- Phase 0: Wq = q[d] * W_basic[d][e] into LDS; mask into LDS ----
    for (int i = t; i < (Dd * MIDe) / 4; i += 256) {          // 8 iters, float4
        const float4 wb = ((const float4*)W_basic)[i];
        const float qd = qB[i >> 4];                          // d = 4i/64
        float4 o;
        o.x = wb.x * qd; o.y = wb.y * qd; o.z = wb.z * qd; o.w = wb.w * qd;
        ((float4*)wqS)[i] = o;
    }
    for (int i = t; i < Mm; i += 256) maskS[i] = maskB[i];
    __syncthreads();

    // ---- Phase 1: GEMM h = relu(key @ Wq + b), fused s[m] and pool accum ----
    // wave w owns m in [49w, 49w+49), 7 groups of 7. lane = e.
    const float wsp = W_spatial[lane];
    const float bb  = b_basic[lane];
    const float bsp = b_spatial[0];
    float poolAcc = 0.f;

    for (int g = 0; g < 7; ++g) {
        const int m0 = 49 * w + 7 * g;
        float acc[7] = {0.f, 0.f, 0.f, 0.f, 0.f, 0.f, 0.f};
        for (int d4 = 0; d4 < 32; ++d4) {
            float4 kv[7];
#pragma unroll
            for (int mi = 0; mi < 7; ++mi)
                kv[mi] = *(const float4*)(keyB + (size_t)(m0 + mi) * Dd + 4 * d4);
            // Wq[4d4+j][e]: stride-1 across lanes -> conflict-free
            const float w0 = wqS[d4 * 256 + lane];
            const float w1 = wqS[d4 * 256 + 64 + lane];
            const float w2 = wqS[d4 * 256 + 128 + lane];
            const float w3 = wqS[d4 * 256 + 192 + lane];
#pragma unroll
            for (int mi = 0; mi < 7; ++mi) {
                acc[mi] = fmaf(kv[mi].x, w0, acc[mi]);
                acc[mi] = fmaf(kv[mi].y, w1, acc[mi]);
                acc[mi] = fmaf(kv[mi].z, w2, acc[mi]);
                acc[mi] = fmaf(kv[mi].w, w3, acc[mi]);
            }
        }
#pragma unroll
        for (int mi = 0; mi < 7; ++mi) {
            const int m = m0 + mi;
            float hv = acc[mi] + bb;
            hv = hv > 0.f ? hv : 0.f;                 // relu
            poolAcc = fmaf(hv, maskS[m], poolAcc);    // masked pool partial
            const float sv = waveReduceSum(hv * wsp); // h[m,:] . W_spatial
            if (lane == 0) sS[m] = sv + bsp;
        }
    }
    poolPart[w][lane] = poolAcc;
    __syncthreads();

    // ---- Phase 2: masked softmax over m; finalize pool ----
    const float myMask = (t < Mm) ? maskS[t] : 0.f;
    float myS = -3.0e38f;
    if (t < Mm) {
        myS = sS[t];
        if (myMask == 0.f) myS = -1.0e9f;
    }
    const float rmx = waveReduceMax(myS);
    if (lane == 0) redS[w] = rmx;
    __syncthreads();
    const float mx = fmaxf(fmaxf(redS[0], redS[1]), fmaxf(redS[2], redS[3]));
    const float ev = (t < Mm) ? __expf(myS - mx) : 0.f;
    const float s1 = waveReduceSum(ev);
    const float s2 = waveReduceSum(myMask);
    if (lane == 0) { redS[4 + w] = s1; redS[8 + w] = s2; }
    __syncthreads();
    const float denom = redS[4] + redS[5] + redS[6] + redS[7];
    const float cnt   = redS[8] + redS[9] + redS[10] + redS[11];
    if (t < Mm) sS[t] = ev / denom;   // alpha, in place (all reads done pre-sync)
    if (t < MIDe)
        poolS[t] = (poolPart[0][t] + poolPart[1][t] + poolPart[2][t] + poolPart[3][t]) / cnt;
    __syncthreads();

    // ---- Phase 3a: channel gate (threads 0..127), kept in register ----
    float chv = 0.f;
    if (t < DVv) {
        float a = b_channel[t];
#pragma unroll 8
        for (int e = 0; e < MIDe; ++e)
            a = fmaf(poolS[e], W_channel[e * DVv + t], a);  // coalesced over t
        chv = 1.f / (1.f + __expf(-a));
    }

    // ---- Phase 3b: v2 = alpha @ value2 (all 256 threads) ----
    const int vq = t & 31;   // float4 column
    const int ms = t >> 5;   // m-stripe 0..7
    float4 acc4 = make_float4(0.f, 0.f, 0.f, 0.f);
    for (int m = ms; m < Mm; m += 8) {
        const float a = sS[m];
        const float4 vv = *(const float4*)(val2B + (size_t)m * DVv + 4 * vq);
        acc4.x = fmaf(a, vv.x, acc4.x);
        acc4.y = fmaf(a, vv.y, acc4.y);
        acc4.z = fmaf(a, vv.z, acc4.z);
        acc4.w = fmaf(a, vv.w, acc4.w);
    }
    ((float4*)&partS[ms][0])[vq] = acc4;
    __syncthreads();

    // ---- Epilogue: out = value1 * v2 * channel_gate ----
    if (t < DVv) {
        float v2v = 0.f;
#pragma unroll
        for (int i = 0; i < 8; ++i) v2v += partS[i][t];
        out[(size_t)bh * DVv + t] = value1[(size_t)bh * DVv + t] * v2v * chv;
    }
}

extern "C" void kernel_launch(void* const* d_in, const int* in_sizes, int n_in,
                              void* d_out, int out_size, void* d_ws, size_t ws_size,
                              hipStream_t stream) {
    const float* query     = (const float*)d_in[0];
    const float* key       = (const float*)d_in[1];
    const float* att_mask  = (const float*)d_in[2];
    const float* value1    = (const float*)d_in[3];
    const float* value2    = (const float*)d_in[4];
    const float* W_basic   = (const float*)d_in[5];
    const float* b_basic   = (const float*)d_in[6];
    const float* W_spatial = (const float*)d_in[7];
    const float* b_spatial = (const float*)d_in[8];
    const float* W_channel = (const float*)d_in[9];
    const float* b_channel = (const float*)d_in[10];
    float* out = (float*)d_out;

    scatt_fused<<<NBH, 256, 0, stream>>>(query, key, att_mask, value1, value2,
                                         W_basic, b_basic, W_spatial, b_spatial,
                                         W_channel, b_channel, out);
}

// Round 2
// 305.962 us; speedup vs baseline: 1.3847x; 1.3847x over previous
//
#include <hip/hip_runtime.h>
#include <cstddef>

// Problem shapes (fixed by reference)
#define NBH  1024   // B*H
#define Mm   196
#define Dd   128
#define MIDe 64
#define DVv  128

__device__ __forceinline__ float waveReduceSum(float v) {
#pragma unroll
    for (int off = 32; off > 0; off >>= 1) v += __shfl_xor(v, off, 64);
    return v;
}

__device__ __forceinline__ float waveReduceMax(float v) {
#pragma unroll
    for (int off = 32; off > 0; off >>= 1) v = fmaxf(v, __shfl_xor(v, off, 64));
    return v;
}

__global__ __launch_bounds__(256, 4)
void scatt_fused(const float* __restrict__ query,
                 const float* __restrict__ key,
                 const float* __restrict__ att_mask,
                 const float* __restrict__ value1,
                 const float* __restrict__ value2,
                 const float* __restrict__ W_basic,
                 const float* __restrict__ b_basic,
                 const float* __restrict__ W_spatial,
                 const float* __restrict__ b_spatial,
                 const float* __restrict__ W_channel,
                 const float* __restrict__ b_channel,
                 float* __restrict__ out)
{
    // wqS (32 KB) is dead after phase 1; partS (4 KB) aliases its start.
    __shared__ __align__(16) float wqS[Dd * MIDe];   // Wq[d][e] = q[d]*W_basic[d][e]
    __shared__ __align__(16) float kS[4][7][Dd];     // 14 KB per-wave key staging
    __shared__ float maskS[Mm];
    __shared__ float sS[Mm];            // spatial logits, then alpha (in place)
    __shared__ float poolPart[4][MIDe];
    __shared__ float poolS[MIDe];
    __shared__ float redS[12];
    float* partS = wqS;                 // [8][DVv] alias, phase 3b only

    const int t    = threadIdx.x;
    const int lane = t & 63;            // = e in phase 1
    const int w    = t >> 6;            // wave id 0..3
    const int bh   = blockIdx.x;
    const int b    = bh >> 3;

    const float* __restrict__ keyB  = key      + (size_t)bh * Mm * Dd;
    const float* __restrict__ val2B = value2   + (size_t)bh * Mm * DVv;
    const float* __restrict__ qB    = query    + (size_t)bh * Dd;
    const float* __restrict__ maskB = att_mask + (size_t)b  * Mm;

    // ---- Phase 0: Wq = q[d] * W_basic[d][e] into LDS; mask into LDS ----
    for (int i = t; i < (Dd * MIDe) / 4; i += 256) {          // 8 iters, float4
        const float4 wb = ((const float4*)W_basic)[i];
        const float qd = qB[i >> 4];                          // d = 4i/64
        float4 o;
        o.x = wb.x * qd; o.y = wb.y * qd; o.z = wb.z * qd; o.w = wb.w * qd;
        ((float4*)wqS)[i] = o;
    }
    for (int i = t; i < Mm; i += 256) maskS[i] = maskB[i];
    __syncthreads();

    // ---- Phase 1: GEMM h = relu(key @ Wq + b), fused s[m] and pool accum ----
    // wave w owns m in [49w, 49w+49), 7 groups of 7 rows. lane = e.
    // Key rows staged per-wave in LDS via coalesced loads (no wave-uniform
    // global loads); rows read back as LDS broadcast b128. No __syncthreads
    // needed: each wave owns kS[w], DS ops within a wave are ordered.
    const float wsp = W_spatial[lane];
    const float bb  = b_basic[lane];
    const float bsp = b_spatial[0];
    float poolAcc = 0.f;

    const int r2 = lane >> 5;           // 0..1: row within pair
    const int c4 = (lane & 31) << 2;    // float col, float4 granule
    float* __restrict__ ksw = &kS[w][0][0];

    // prefetch group 0 (7 rows: 3 x b128 covering rows 0..5, 1 x b64 row 6)
    const float* gp = keyB + (size_t)(49 * w) * Dd;
    float4 p0 = *(const float4*)(gp + (0 + r2) * Dd + c4);
    float4 p1 = *(const float4*)(gp + (2 + r2) * Dd + c4);
    float4 p2 = *(const float4*)(gp + (4 + r2) * Dd + c4);
    float2 p3 = *(const float2*)(gp + 6 * Dd + 2 * lane);

    for (int g = 0; g < 7; ++g) {
        // stage prefetched rows into this wave's LDS buffer
        *(float4*)(ksw + (0 + r2) * Dd + c4) = p0;
        *(float4*)(ksw + (2 + r2) * Dd + c4) = p1;
        *(float4*)(ksw + (4 + r2) * Dd + c4) = p2;
        *(float2*)(ksw + 6 * Dd + 2 * lane)  = p3;
        if (g < 6) {  // prefetch next group; latency hides behind compute
            const float* gn = keyB + (size_t)(49 * w + 7 * (g + 1)) * Dd;
            p0 = *(const float4*)(gn + (0 + r2) * Dd + c4);
            p1 = *(const float4*)(gn + (2 + r2) * Dd + c4);
            p2 = *(const float4*)(gn + (4 + r2) * Dd + c4);
            p3 = *(const float2*)(gn + 6 * Dd + 2 * lane);
        }

        float acc[7] = {0.f, 0.f, 0.f, 0.f, 0.f, 0.f, 0.f};
#pragma unroll 2
        for (int d4 = 0; d4 < 32; ++d4) {
            // key row fragments: wave-uniform address -> LDS broadcast b128
            float4 kv[7];
#pragma unroll
            for (int mi = 0; mi < 7; ++mi)
                kv[mi] = *(const float4*)(ksw + mi * Dd + 4 * d4);
            // Wq[4d4+j][e]: stride-1 across lanes -> 2-way aliasing, free
            const float w0 = wqS[d4 * 256 + lane];
            const float w1 = wqS[d4 * 256 + 64 + lane];
            const float w2 = wqS[d4 * 256 + 128 + lane];
            const float w3 = wqS[d4 * 256 + 192 + lane];
#pragma unroll
            for (int mi = 0; mi < 7; ++mi) {
                acc[mi] = fmaf(kv[mi].x, w0, acc[mi]);
                acc[mi] = fmaf(kv[mi].y, w1, acc[mi]);
                acc[mi] = fmaf(kv[mi].z, w2, acc[mi]);
                acc[mi] = fmaf(kv[mi].w, w3, acc[mi]);
            }
        }
#pragma unroll
        for (int mi = 0; mi < 7; ++mi) {
            const int m = 49 * w + 7 * g + mi;
            float hv = acc[mi] + bb;
            hv = hv > 0.f ? hv : 0.f;                 // relu
            poolAcc = fmaf(hv, maskS[m], poolAcc);    // masked pool partial
            const float sv = waveReduceSum(hv * wsp); // h[m,:] . W_spatial
            if (lane == 0) sS[m] = sv + bsp;
        }
    }
    poolPart[w][lane] = poolAcc;
    __syncthreads();

    // ---- Phase 2: masked softmax over m; finalize pool ----
    const float myMask = (t < Mm) ? maskS[t] : 0.f;
    float myS = -3.0e38f;
    if (t < Mm) {
        myS = sS[t];
        if (myMask == 0.f) myS = -1.0e9f;
    }
    const float rmx = waveReduceMax(myS);
    if (lane == 0) redS[w] = rmx;
    __syncthreads();
    const float mx = fmaxf(fmaxf(redS[0], redS[1]), fmaxf(redS[2], redS[3]));
    const float ev = (t < Mm) ? __expf(myS - mx) : 0.f;
    const float s1 = waveReduceSum(ev);
    const float s2 = waveReduceSum(myMask);
    if (lane == 0) { redS[4 + w] = s1; redS[8 + w] = s2; }
    __syncthreads();
    const float denom = redS[4] + redS[5] + redS[6] + redS[7];
    const float cnt   = redS[8] + redS[9] + redS[10] + redS[11];
    if (t < Mm) sS[t] = ev / denom;   // alpha, in place (all reads done pre-sync)
    if (t < MIDe)
        poolS[t] = (poolPart[0][t] + poolPart[1][t] + poolPart[2][t] + poolPart[3][t]) / cnt;
    __syncthreads();   // also guards partS alias: wqS fully dead after phase 1

    // ---- Phase 3a: channel gate (threads 0..127), kept in register ----
    float chv = 0.f;
    if (t < DVv) {
        float a = b_channel[t];
#pragma unroll 8
        for (int e = 0; e < MIDe; ++e)
            a = fmaf(poolS[e], W_channel[e * DVv + t], a);  // coalesced over t
        chv = 1.f / (1.f + __expf(-a));
    }

    // ---- Phase 3b: v2 = alpha @ value2 (all 256 threads) ----
    const int vq = t & 31;   // float4 column
    const int ms = t >> 5;   // m-stripe 0..7
    float4 acc4 = make_float4(0.f, 0.f, 0.f, 0.f);
    for (int m = ms; m < Mm; m += 8) {
        const float a = sS[m];
        const float4 vv = *(const float4*)(val2B + (size_t)m * DVv + 4 * vq);
        acc4.x = fmaf(a, vv.x, acc4.x);
        acc4.y = fmaf(a, vv.y, acc4.y);
        acc4.z = fmaf(a, vv.z, acc4.z);
        acc4.w = fmaf(a, vv.w, acc4.w);
    }
    ((float4*)&partS[ms * DVv])[vq] = acc4;
    __syncthreads();

    // ---- Epilogue: out = value1 * v2 * channel_gate ----
    if (t < DVv) {
        float v2v = 0.f;
#pragma unroll
        for (int i = 0; i < 8; ++i) v2v += partS[i * DVv + t];
        out[(size_t)bh * DVv + t] = value1[(size_t)bh * DVv + t] * v2v * chv;
    }
}

extern "C" void kernel_launch(void* const* d_in, const int* in_sizes, int n_in,
                              void* d_out, int out_size, void* d_ws, size_t ws_size,
                              hipStream_t stream) {
    const float* query     = (const float*)d_in[0];
    const float* key       = (const float*)d_in[1];
    const float* att_mask  = (const float*)d_in[2];
    const float* value1    = (const float*)d_in[3];
    const float* value2    = (const float*)d_in[4];
    const float* W_basic   = (const float*)d_in[5];
    const float* b_basic   = (const float*)d_in[6];
    const float* W_spatial = (const float*)d_in[7];
    const float* b_spatial = (const float*)d_in[8];
    const float* W_channel = (const float*)d_in[9];
    const float* b_channel = (const float*)d_in[10];
    float* out = (float*)d_out;

    scatt_fused<<<NBH, 256, 0, stream>>>(query, key, att_mask, value1, value2,
                                         W_basic, b_basic, W_spatial, b_spatial,
                                         W_channel, b_channel, out);
}

// Round 3
// 263.494 us; speedup vs baseline: 1.6079x; 1.1612x over previous
//
#include <hip/hip_runtime.h>
#include <cstddef>

// Problem shapes (fixed by reference)
#define NBH  1024   // B*H
#define Mm   196
#define Dd   128
#define MIDe 64
#define DVv  128

typedef __attribute__((ext_vector_type(8))) short bf16x8;  // 8 bf16 in 4 VGPRs
typedef __attribute__((ext_vector_type(4))) float f32x4;   // MFMA C/D frag

__device__ __forceinline__ short f2bf(float x) {           // fp32 -> bf16 RNE
    union { float f; unsigned u; } v; v.f = x;
    return (short)((v.u + 0x7FFFu + ((v.u >> 16) & 1u)) >> 16);
}

__device__ __forceinline__ float waveReduceSum(float v) {
#pragma unroll
    for (int off = 32; off > 0; off >>= 1) v += __shfl_xor(v, off, 64);
    return v;
}

__device__ __forceinline__ float waveReduceMax(float v) {
#pragma unroll
    for (int off = 32; off > 0; off >>= 1) v = fmaxf(v, __shfl_xor(v, off, 64));
    return v;
}

__global__ __launch_bounds__(256, 3)
void scatt_fused(const float* __restrict__ query,
                 const float* __restrict__ key,
                 const float* __restrict__ att_mask,
                 const float* __restrict__ value1,
                 const float* __restrict__ value2,
                 const float* __restrict__ W_basic,
                 const float* __restrict__ b_basic,
                 const float* __restrict__ W_spatial,
                 const float* __restrict__ b_spatial,
                 const float* __restrict__ W_channel,
                 const float* __restrict__ b_channel,
                 float* __restrict__ out)
{
    __shared__ float maskS[Mm];
    __shared__ float sS[Mm];            // spatial logits, then alpha (in place)
    __shared__ float poolPart[4][MIDe];
    __shared__ float poolS[MIDe];
    __shared__ float partS[8][DVv];     // v2 partial sums
    __shared__ float redS[12];

    const int t    = threadIdx.x;
    const int lane = t & 63;
    const int w    = t >> 6;            // wave id 0..3
    const int ln15 = lane & 15;
    const int q4   = lane >> 4;         // quad id 0..3
    const int bh   = blockIdx.x;
    const int b    = bh >> 3;

    const float* __restrict__ keyB  = key      + (size_t)bh * Mm * Dd;
    const float* __restrict__ val2B = value2   + (size_t)bh * Mm * DVv;
    const float* __restrict__ qB    = query    + (size_t)bh * Dd;
    const float* __restrict__ maskB = att_mask + (size_t)b  * Mm;

    for (int i = t; i < Mm; i += 256) maskS[i] = maskB[i];

    // ---- Build B-fragments in registers: Wq[k][n] = q[k]*W_basic[k][n], bf16.
    // B-frag layout: lane holds B[k = ks*32 + q4*8 + j][n = nt*16 + ln15].
    // W_basic is 32 KB, L2/L3-hot across all 1024 blocks; loads over ln15 are
    // 64B-coalesced per quad.
    bf16x8 bfr[4][4];                   // [ks][nt], 64 VGPRs, resident
#pragma unroll
    for (int ks = 0; ks < 4; ++ks) {
        const int kb = ks * 32 + q4 * 8;
        float qv[8];
        *(float4*)&qv[0] = *(const float4*)(qB + kb);
        *(float4*)&qv[4] = *(const float4*)(qB + kb + 4);
#pragma unroll
        for (int nt = 0; nt < 4; ++nt) {
            const int n = nt * 16 + ln15;
            bf16x8 f;
#pragma unroll
            for (int j = 0; j < 8; ++j)
                f[j] = f2bf(qv[j] * W_basic[(kb + j) * MIDe + n]);
            bfr[ks][nt] = f;
        }
    }
    float bbv[4], wspv[4];
#pragma unroll
    for (int nt = 0; nt < 4; ++nt) {
        bbv[nt]  = b_basic[nt * 16 + ln15];
        wspv[nt] = W_spatial[nt * 16 + ln15];
    }
    const float bsp = b_spatial[0];
    float poolAcc[4] = {0.f, 0.f, 0.f, 0.f};

    __syncthreads();   // maskS ready

    // ---- Phase 1: h = relu(key @ Wq + b) via MFMA; fused s[m], pool.
    // M = 196 -> 13 tiles of 16 (tile 12 padded; rows clamped, masked out).
    // Wave w owns m-tiles {w, w+4, w+8, w+12<13}. A-frags straight from
    // global: lane reads key[mt*16+ln15][ks*32 + q4*8 .. +8].
    for (int mt = w; mt < 13; mt += 4) {
        f32x4 acc[4] = {f32x4{0,0,0,0}, f32x4{0,0,0,0},
                        f32x4{0,0,0,0}, f32x4{0,0,0,0}};
        const int mrow = min(mt * 16 + ln15, Mm - 1);
        const float* ap = keyB + (size_t)mrow * Dd + q4 * 8;
#pragma unroll
        for (int ks = 0; ks < 4; ++ks) {
            const float4 a0 = *(const float4*)(ap + ks * 32);
            const float4 a1 = *(const float4*)(ap + ks * 32 + 4);
            const bf16x8 af = { f2bf(a0.x), f2bf(a0.y), f2bf(a0.z), f2bf(a0.w),
                                f2bf(a1.x), f2bf(a1.y), f2bf(a1.z), f2bf(a1.w) };
#pragma unroll
            for (int nt = 0; nt < 4; ++nt)
                acc[nt] = __builtin_amdgcn_mfma_f32_16x16x32_bf16(
                              af, bfr[ks][nt], acc[nt], 0, 0, 0);
        }
        // Epilogue: C/D layout col = ln15 (e within n-tile), row = q4*4 + r.
#pragma unroll
        for (int r = 0; r < 4; ++r) {
            const int m = mt * 16 + q4 * 4 + r;
            const bool valid = m < Mm;
            const float msk = valid ? maskS[m] : 0.f;
            float srow = 0.f;
#pragma unroll
            for (int nt = 0; nt < 4; ++nt) {
                float hv = acc[nt][r] + bbv[nt];
                hv = hv > 0.f ? hv : 0.f;                 // relu
                poolAcc[nt] = fmaf(hv, msk, poolAcc[nt]); // masked pool partial
                srow = fmaf(hv, wspv[nt], srow);          // h[m,:].W_spatial
            }
            srow += __shfl_xor(srow, 1, 64);
            srow += __shfl_xor(srow, 2, 64);
            srow += __shfl_xor(srow, 4, 64);
            srow += __shfl_xor(srow, 8, 64);
            if (valid && ln15 == 0) sS[m] = srow + bsp;
        }
    }
    // pool: reduce the 4 row-quads (same e, different m) across q4
#pragma unroll
    for (int nt = 0; nt < 4; ++nt) {
        poolAcc[nt] += __shfl_xor(poolAcc[nt], 16, 64);
        poolAcc[nt] += __shfl_xor(poolAcc[nt], 32, 64);
    }
    if (lane < 16) {
#pragma unroll
        for (int nt = 0; nt < 4; ++nt)
            poolPart[w][nt * 16 + lane] = poolAcc[nt];
    }
    __syncthreads();

    // ---- Phase 2: masked softmax over m; finalize pool ----
    const float myMask = (t < Mm) ? maskS[t] : 0.f;
    float myS = -3.0e38f;
    if (t < Mm) {
        myS = sS[t];
        if (myMask == 0.f) myS = -1.0e9f;
    }
    const float rmx = waveReduceMax(myS);
    if (lane == 0) redS[w] = rmx;
    __syncthreads();
    const float mx = fmaxf(fmaxf(redS[0], redS[1]), fmaxf(redS[2], redS[3]));
    const float ev = (t < Mm) ? __expf(myS - mx) : 0.f;
    const float s1 = waveReduceSum(ev);
    const float s2 = waveReduceSum(myMask);
    if (lane == 0) { redS[4 + w] = s1; redS[8 + w] = s2; }
    __syncthreads();
    const float denom = redS[4] + redS[5] + redS[6] + redS[7];
    const float cnt   = redS[8] + redS[9] + redS[10] + redS[11];
    if (t < Mm) sS[t] = ev / denom;   // alpha, in place (all reads done pre-sync)
    if (t < MIDe)
        poolS[t] = (poolPart[0][t] + poolPart[1][t] + poolPart[2][t] + poolPart[3][t]) / cnt;
    __syncthreads();

    // ---- Phase 3a: channel gate (threads 0..127), kept in register ----
    float chv = 0.f;
    if (t < DVv) {
        float a = b_channel[t];
#pragma unroll 8
        for (int e = 0; e < MIDe; ++e)
            a = fmaf(poolS[e], W_channel[e * DVv + t], a);  // coalesced over t
        chv = 1.f / (1.f + __expf(-a));
    }

    // ---- Phase 3b: v2 = alpha @ value2 (all 256 threads) ----
    const int vq = t & 31;   // float4 column
    const int ms = t >> 5;   // m-stripe 0..7
    float4 acc4 = make_float4(0.f, 0.f, 0.f, 0.f);
    for (int m = ms; m < Mm; m += 8) {
        const float a = sS[m];
        const float4 vv = *(const float4*)(val2B + (size_t)m * DVv + 4 * vq);
        acc4.x = fmaf(a, vv.x, acc4.x);
        acc4.y = fmaf(a, vv.y, acc4.y);
        acc4.z = fmaf(a, vv.z, acc4.z);
        acc4.w = fmaf(a, vv.w, acc4.w);
    }
    ((float4*)&partS[ms][0])[vq] = acc4;
    __syncthreads();

    // ---- Epilogue: out = value1 * v2 * channel_gate ----
    if (t < DVv) {
        float v2v = 0.f;
#pragma unroll
        for (int i = 0; i < 8; ++i) v2v += partS[i][t];
        out[(size_t)bh * DVv + t] = value1[(size_t)bh * DVv + t] * v2v * chv;
    }
}

extern "C" void kernel_launch(void* const* d_in, const int* in_sizes, int n_in,
                              void* d_out, int out_size, void* d_ws, size_t ws_size,
                              hipStream_t stream) {
    const float* query     = (const float*)d_in[0];
    const float* key       = (const float*)d_in[1];
    const float* att_mask  = (const float*)d_in[2];
    const float* value1    = (const float*)d_in[3];
    const float* value2    = (const float*)d_in[4];
    const float* W_basic   = (const float*)d_in[5];
    const float* b_basic   = (const float*)d_in[6];
    const float* W_spatial = (const float*)d_in[7];
    const float* b_spatial = (const float*)d_in[8];
    const float* W_channel = (const float*)d_in[9];
    const float* b_channel = (const float*)d_in[10];
    float* out = (float*)d_out;

    scatt_fused<<<NBH, 256, 0, stream>>>(query, key, att_mask, value1, value2,
                                         W_basic, b_basic, W_spatial, b_spatial,
                                         W_channel, b_channel, out);
}

// Round 4
// 243.949 us; speedup vs baseline: 1.7367x; 1.0801x over previous
//
#include <hip/hip_runtime.h>
#include <cstddef>

// Problem shapes (fixed by reference)
#define NBH  1024   // B*H
#define Mm   196
#define Dd   128
#define MIDe 64
#define DVv  128
#define WQLD 136    // WqT row length in shorts (128 + 8 pad -> 272 B rows,
                    // 272 % 128 = 16B: rotates banks by 4/row -> frag reads
                    // and builds are aggregate-conflict-free)

typedef __attribute__((ext_vector_type(8))) short bf16x8;  // 8 bf16 in 4 VGPRs
typedef __attribute__((ext_vector_type(4))) float f32x4;   // MFMA C/D frag

__device__ __forceinline__ short f2bf(float x) {           // fp32 -> bf16 RNE
    union { float f; unsigned u; } v; v.f = x;
    return (short)((v.u + 0x7FFFu + ((v.u >> 16) & 1u)) >> 16);
}

__device__ __forceinline__ float waveReduceSum(float v) {
#pragma unroll
    for (int off = 32; off > 0; off >>= 1) v += __shfl_xor(v, off, 64);
    return v;
}

__device__ __forceinline__ float waveReduceMax(float v) {
#pragma unroll
    for (int off = 32; off > 0; off >>= 1) v = fmaxf(v, __shfl_xor(v, off, 64));
    return v;
}

__global__ __launch_bounds__(256, 4)
void scatt_fused(const float* __restrict__ query,
                 const float* __restrict__ key,
                 const float* __restrict__ att_mask,
                 const float* __restrict__ value1,
                 const float* __restrict__ value2,
                 const float* __restrict__ W_basic,
                 const float* __restrict__ b_basic,
                 const float* __restrict__ W_spatial,
                 const float* __restrict__ b_spatial,
                 const float* __restrict__ W_channel,
                 const float* __restrict__ b_channel,
                 float* __restrict__ out)
{
    __shared__ short wqT[MIDe][WQLD];   // bf16 Wq^T[e][d], built once per block
    __shared__ float qS[Dd];
    __shared__ float maskS[Mm];
    __shared__ float sS[Mm];            // spatial logits, then alpha (in place)
    __shared__ float poolPart[4][MIDe];
    __shared__ float poolS[MIDe];
    __shared__ float partS[8][DVv];     // v2 partial sums
    __shared__ float redS[12];

    const int t    = threadIdx.x;
    const int lane = t & 63;
    const int w    = t >> 6;            // wave id 0..3
    const int ln15 = lane & 15;
    const int q4   = lane >> 4;         // quad id 0..3
    const int bh   = blockIdx.x;
    const int b    = bh >> 3;

    const float* __restrict__ keyB  = key      + (size_t)bh * Mm * Dd;
    const float* __restrict__ val2B = value2   + (size_t)bh * Mm * DVv;
    const float* __restrict__ qB    = query    + (size_t)bh * Dd;
    const float* __restrict__ maskB = att_mask + (size_t)b  * Mm;

    // ---- Phase 0a: stage q + mask ----
    if (t < 32) ((float4*)qS)[t] = ((const float4*)qB)[t];
    for (int i = t; i < Mm; i += 256) maskS[i] = maskB[i];
    __syncthreads();

    // ---- Phase 0b: build WqT[e][d] = bf16(q[d]*W_basic[d][e]) cooperatively.
    // Wave w owns d in [32w, 32w+32) for ALL e: per iteration one fully
    // coalesced 256B load of W_basic row d (lane = e), q[d] broadcast from LDS.
    // Built ONCE per block (R3 built all frags redundantly per wave).
    {
        const int e0 = lane;            // e column this thread fills
        const int d0 = w * 32;
#pragma unroll
        for (int c = 0; c < 4; ++c) {   // 4 chunks of 8 d-values
            short pk[8];
#pragma unroll
            for (int j = 0; j < 8; ++j) {
                const int d = d0 + c * 8 + j;
                pk[j] = f2bf(qS[d] * W_basic[d * MIDe + e0]);
            }
            *(bf16x8*)&wqT[e0][d0 + c * 8] = *(bf16x8*)pk;  // ds_write_b128
        }
    }
    __syncthreads();

    // ---- B-fragments from LDS (held in registers for all of phase 1).
    // frag[ks][nt][j] = Wq[k = ks*32+q4*8+j][n = nt*16+ln15]  (MFMA B layout)
    // = WqT[n][k..k+7]: one ds_read_b128 each, aggregate-conflict-free.
    bf16x8 bfr[4][4];
#pragma unroll
    for (int ks = 0; ks < 4; ++ks)
#pragma unroll
        for (int nt = 0; nt < 4; ++nt)
            bfr[ks][nt] = *(const bf16x8*)&wqT[nt * 16 + ln15][ks * 32 + q4 * 8];

    float bbv[4], wspv[4];
#pragma unroll
    for (int nt = 0; nt < 4; ++nt) {
        bbv[nt]  = b_basic[nt * 16 + ln15];
        wspv[nt] = W_spatial[nt * 16 + ln15];
    }
    const float bsp = b_spatial[0];
    float poolAcc[4] = {0.f, 0.f, 0.f, 0.f};

    // ---- Phase 1: h = relu(key @ Wq + b) via MFMA; fused s[m], pool.
    // M = 196 -> 13 m-tiles of 16. Wave w owns tiles {w, w+4, w+8, w+12<13}.
    // All 8 A-loads of a tile are hoisted -> single vmcnt batch per tile.
    for (int mt = w; mt < 13; mt += 4) {
        const int mrow = min(mt * 16 + ln15, Mm - 1);
        const float* ap = keyB + (size_t)mrow * Dd + q4 * 8;
        float4 a0[4], a1[4];
#pragma unroll
        for (int ks = 0; ks < 4; ++ks) {
            a0[ks] = *(const float4*)(ap + ks * 32);
            a1[ks] = *(const float4*)(ap + ks * 32 + 4);
        }
        f32x4 acc[4] = {f32x4{0,0,0,0}, f32x4{0,0,0,0},
                        f32x4{0,0,0,0}, f32x4{0,0,0,0}};
#pragma unroll
        for (int ks = 0; ks < 4; ++ks) {
            const bf16x8 af = { f2bf(a0[ks].x), f2bf(a0[ks].y),
                                f2bf(a0[ks].z), f2bf(a0[ks].w),
                                f2bf(a1[ks].x), f2bf(a1[ks].y),
                                f2bf(a1[ks].z), f2bf(a1[ks].w) };
#pragma unroll
            for (int nt = 0; nt < 4; ++nt)
                acc[nt] = __builtin_amdgcn_mfma_f32_16x16x32_bf16(
                              af, bfr[ks][nt], acc[nt], 0, 0, 0);
        }
        // Epilogue: C/D layout col = ln15 (e within n-tile), row = q4*4 + r.
#pragma unroll
        for (int r = 0; r < 4; ++r) {
            const int m = mt * 16 + q4 * 4 + r;
            const bool valid = m < Mm;
            const float msk = valid ? maskS[m] : 0.f;
            float srow = 0.f;
#pragma unroll
            for (int nt = 0; nt < 4; ++nt) {
                float hv = acc[nt][r] + bbv[nt];
                hv = hv > 0.f ? hv : 0.f;                 // relu
                poolAcc[nt] = fmaf(hv, msk, poolAcc[nt]); // masked pool partial
                srow = fmaf(hv, wspv[nt], srow);          // h[m,:].W_spatial
            }
            srow += __shfl_xor(srow, 1, 64);
            srow += __shfl_xor(srow, 2, 64);
            srow += __shfl_xor(srow, 4, 64);
            srow += __shfl_xor(srow, 8, 64);
            if (valid && ln15 == 0) sS[m] = srow + bsp;
        }
    }
    // pool: reduce the 4 row-quads (same e, different m) across q4
#pragma unroll
    for (int nt = 0; nt < 4; ++nt) {
        poolAcc[nt] += __shfl_xor(poolAcc[nt], 16, 64);
        poolAcc[nt] += __shfl_xor(poolAcc[nt], 32, 64);
    }
    if (lane < 16) {
#pragma unroll
        for (int nt = 0; nt < 4; ++nt)
            poolPart[w][nt * 16 + lane] = poolAcc[nt];
    }
    __syncthreads();

    // ---- Phase 2: masked softmax over m; finalize pool ----
    const float myMask = (t < Mm) ? maskS[t] : 0.f;
    float myS = -3.0e38f;
    if (t < Mm) {
        myS = sS[t];
        if (myMask == 0.f) myS = -1.0e9f;
    }
    const float rmx = waveReduceMax(myS);
    if (lane == 0) redS[w] = rmx;
    __syncthreads();
    const float mx = fmaxf(fmaxf(redS[0], redS[1]), fmaxf(redS[2], redS[3]));
    const float ev = (t < Mm) ? __expf(myS - mx) : 0.f;
    const float s1 = waveReduceSum(ev);
    const float s2 = waveReduceSum(myMask);
    if (lane == 0) { redS[4 + w] = s1; redS[8 + w] = s2; }
    __syncthreads();
    const float denom = redS[4] + redS[5] + redS[6] + redS[7];
    const float cnt   = redS[8] + redS[9] + redS[10] + redS[11];
    if (t < Mm) sS[t] = ev / denom;   // alpha, in place (all reads done pre-sync)
    if (t < MIDe)
        poolS[t] = (poolPart[0][t] + poolPart[1][t] + poolPart[2][t] + poolPart[3][t]) / cnt;
    __syncthreads();

    // ---- Phase 3a: channel gate (threads 0..127, waves 0-1), in register;
    // waves 2-3 proceed straight into 3b -> natural overlap.
    float chv = 0.f;
    if (t < DVv) {
        float a = b_channel[t];
#pragma unroll 8
        for (int e = 0; e < MIDe; ++e)
            a = fmaf(poolS[e], W_channel[e * DVv + t], a);  // coalesced over t
        chv = 1.f / (1.f + __expf(-a));
    }

    // ---- Phase 3b: v2 = alpha @ value2 (all 256 threads) ----
    const int vq = t & 31;   // float4 column
    const int ms = t >> 5;   // m-stripe 0..7
    float4 acc4 = make_float4(0.f, 0.f, 0.f, 0.f);
#pragma unroll 5
    for (int m = ms; m < Mm; m += 8) {
        const float a = sS[m];
        const float4 vv = *(const float4*)(val2B + (size_t)m * DVv + 4 * vq);
        acc4.x = fmaf(a, vv.x, acc4.x);
        acc4.y = fmaf(a, vv.y, acc4.y);
        acc4.z = fmaf(a, vv.z, acc4.z);
        acc4.w = fmaf(a, vv.w, acc4.w);
    }
    ((float4*)&partS[ms][0])[vq] = acc4;
    __syncthreads();

    // ---- Epilogue: out = value1 * v2 * channel_gate ----
    if (t < DVv) {
        float v2v = 0.f;
#pragma unroll
        for (int i = 0; i < 8; ++i) v2v += partS[i][t];
        out[(size_t)bh * DVv + t] = value1[(size_t)bh * DVv + t] * v2v * chv;
    }
}

extern "C" void kernel_launch(void* const* d_in, const int* in_sizes, int n_in,
                              void* d_out, int out_size, void* d_ws, size_t ws_size,
                              hipStream_t stream) {
    const float* query     = (const float*)d_in[0];
    const float* key       = (const float*)d_in[1];
    const float* att_mask  = (const float*)d_in[2];
    const float* value1    = (const float*)d_in[3];
    const float* value2    = (const float*)d_in[4];
    const float* W_basic   = (const float*)d_in[5];
    const float* b_basic   = (const float*)d_in[6];
    const float* W_spatial = (const float*)d_in[7];
    const float* b_spatial = (const float*)d_in[8];
    const float* W_channel = (const float*)d_in[9];
    const float* b_channel = (const float*)d_in[10];
    float* out = (float*)d_out;

    scatt_fused<<<NBH, 256, 0, stream>>>(query, key, att_mask, value1, value2,
                                         W_basic, b_basic, W_spatial, b_spatial,
                                         W_channel, b_channel, out);
}